// Round 3
// baseline (250.265 us; speedup 1.0000x reference)
//
#include <hip/hip_runtime.h>

// NetVladCNN: B=64, D=512, H=W=32 (N=1024), K=64
// K0 : pack w f32 -> bf16 image [16 dblk][64 k][32 d] (unpadded, 64 KB)
// F1 : FUSED feat+softmax. grid 256 = (b 64)x(ws 4); block 512 thr = 8 waves.
//      Block tile: 64k x 256n where n-set = all 32 h x 8 w-cols (w = ws*8..+8)
//      -> softmax over h is block-local. x staged via glds 3-buf ring, counted
//      vmcnt(8); XOR-swizzled global source keeps LDS linear (glds constraint)
//      and frag reads 2-way-conflict-free. feat never touches global.
//      Writes a bf16 image [b][h 32][k 64][w 32] via LDS slab (coalesced).
// K2 : V = a @ x^T - 32*c; barrier-free, LDS-free; a direct from L2, x via
//      depth-4 reg ring; fused L2-normalize over k. -> yw (B,K,D)
// K3 : transpose -> out (D,K,B)

typedef __attribute__((ext_vector_type(8))) short short8;
typedef __attribute__((ext_vector_type(4))) float f32x4;
typedef unsigned short u16;
typedef unsigned int u32;

union S8u { u32 q[4]; short8 s; };

__device__ __forceinline__ u32 pk2(float lo, float hi) {  // RNE bf16 pair pack
  union { float f; u32 u; } a, b; a.f = lo; b.f = hi;
  u32 xl = (a.u + 0x7fffu + ((a.u >> 16) & 1u)) >> 16;
  u32 xh = (b.u + 0x7fffu + ((b.u >> 16) & 1u)) & 0xffff0000u;
  return xl | xh;
}

__device__ __forceinline__ u16 bf1(float f) {
  union { float f; u32 u; } a; a.f = f;
  return (u16)((a.u + 0x7fffu + ((a.u >> 16) & 1u)) >> 16);
}

typedef const __attribute__((address_space(1))) u32 GU32;
typedef __attribute__((address_space(3))) u32 LU32;
__device__ __forceinline__ void glds16(const void* g, void* l) {
  __builtin_amdgcn_global_load_lds((GU32*)g, (LU32*)l, 16, 0, 0);
}

// ---------------- K0: pack w into unpadded bf16 image ----------------
// wsw image: [i=d-block 16][k 64][32 d] u16 = 64 KB
__global__ __launch_bounds__(256) void k0_packw(
    const float* __restrict__ w, u16* __restrict__ wsw)
{
  const int tg = blockIdx.x * 256 + threadIdx.x;   // 8192 threads
  const int dd4 = tg & 7, i = (tg >> 3) & 15, k = tg >> 7;
  f32x4 v = *(const f32x4*)(w + k * 512 + i * 32 + dd4 * 4);
  u32* dst = (u32*)(wsw + (size_t)(i * 64 + k) * 32 + dd4 * 4);
  dst[0] = pk2(v[0], v[1]);
  dst[1] = pk2(v[2], v[3]);
}

// ---------------- F1: fused features GEMM + softmax ----------------
// n_loc enumeration: n_loc = h*8 + wo  (wo 0..7, w = ws*8+wo), 256 per block.
// wave wv owns n_loc in [wv*32, wv*32+32); acc tiles: 4 mt (k) x 2 nt.
// LDS x-buf: [3][32 d][256 n'] f32, n' = n_loc ^ (q_d<<4), q_d=(d_loc>>3).
__global__ __launch_bounds__(512, 1) void f1_feat_softmax(
    const float* __restrict__ x, const u16* __restrict__ wsw,
    u16* __restrict__ apad)
{
  const int blk = blockIdx.x;
  const int b = (blk & 7) | (((blk >> 3) & 7) << 3);   // XCD = b%8
  const int ws = blk >> 6;                             // w-set 0..3
  const int tid = threadIdx.x, lane = tid & 63, wv = tid >> 6;
  const int cc = lane & 15, q = lane >> 4;
  const int wo = cc & 7, hh = cc >> 3;

  __shared__ __align__(16) char smem[96 * 1024];       // 3 x 32 KB x-ring

  const char* xb = (const char*)(x + ((size_t)b << 19));

  f32x4 acc[4][2];
#pragma unroll
  for (int mt = 0; mt < 4; mt++)
#pragma unroll
    for (int nt = 0; nt < 2; nt++) acc[mt][nt] = (f32x4){0.f, 0.f, 0.f, 0.f};

  short8 wf[4][4];                                     // w-frag ring

  // stage s: 32 d-rows; wave stages rows d_loc = wv + 8j. Source chunk
  // csrc = lane ^ (j<<2) realizes LDS word m = n_loc ^ (j<<4) with linear
  // glds dest (base + lane*16). 32B-contiguous lane pairs; ws-siblings
  // fill the rest of each 128B segment in the same XCD's L2.
#define STAGEX(s)                                                              \
  {                                                                            \
    char* lb = smem + ((s) % 3) * 32768;                                       \
    _Pragma("unroll")                                                          \
    for (int j = 0; j < 4; j++) {                                              \
      const int csrc = lane ^ (j << 2);                                        \
      glds16(xb + (size_t)((s) * 32 + wv + 8 * j) * 4096                       \
                 + (csrc >> 1) * 128 + ws * 32 + (csrc & 1) * 16,              \
             lb + (wv + 8 * j) * 1024 + lane * 16);                            \
    }                                                                          \
  }
#define LOADWF(s)                                                              \
  {                                                                            \
    _Pragma("unroll")                                                          \
    for (int mt = 0; mt < 4; mt++)                                             \
      wf[(s) & 3][mt] = *(const short8*)(                                      \
          wsw + (size_t)(((s) * 64 + mt * 16 + cc) * 32 + q * 8));             \
  }

  LOADWF(0); __builtin_amdgcn_sched_barrier(0);
  STAGEX(0); __builtin_amdgcn_sched_barrier(0);
  LOADWF(1); __builtin_amdgcn_sched_barrier(0);
  STAGEX(1); __builtin_amdgcn_sched_barrier(0);

#pragma unroll
  for (int i = 0; i < 16; i++) {
    // drain pair (lw(i), st(i)); keep (lw(i+1), st(i+1)) in flight
    if (i == 15) asm volatile("s_waitcnt vmcnt(0)" ::: "memory");
    else         asm volatile("s_waitcnt vmcnt(8)" ::: "memory");
    __builtin_amdgcn_s_barrier();
    __builtin_amdgcn_sched_barrier(0);
    if (i < 14) {
      LOADWF(i + 2); __builtin_amdgcn_sched_barrier(0);
      STAGEX(i + 2); __builtin_amdgcn_sched_barrier(0);
    }

    const float* xsb = (const float*)(smem + (i % 3) * 32768);
    short8 bfv[2];
#pragma unroll
    for (int nt = 0; nt < 2; nt++) {
      const int colx = (wv * 32 + nt * 16 + cc) ^ (q << 4);
      const float* xc = xsb + colx;
      const int d0 = q * 8;
      float v0 = xc[(d0 + 0) * 256], v1 = xc[(d0 + 1) * 256];
      float v2 = xc[(d0 + 2) * 256], v3 = xc[(d0 + 3) * 256];
      float v4 = xc[(d0 + 4) * 256], v5 = xc[(d0 + 5) * 256];
      float v6 = xc[(d0 + 6) * 256], v7 = xc[(d0 + 7) * 256];
      S8u t;
      t.q[0] = pk2(v0, v1); t.q[1] = pk2(v2, v3);
      t.q[2] = pk2(v4, v5); t.q[3] = pk2(v6, v7);
      bfv[nt] = t.s;
    }
#pragma unroll
    for (int nt = 0; nt < 2; nt++)
#pragma unroll
      for (int mt = 0; mt < 4; mt++)
        acc[mt][nt] = __builtin_amdgcn_mfma_f32_16x16x32_bf16(wf[i & 3][mt], bfv[nt], acc[mt][nt], 0, 0, 0);
  }
#undef STAGEX
#undef LOADWF

  // acc[mt][nt][r] = feat(k = mt*16+q*4+r, n_loc = wv*32+nt*16+cc)
  // h = wv*4 + nt*2 + hh ; w-col = wo. Softmax over h per (k, wo).
  __syncthreads();                       // x-ring dead; alias scratch
  float* scr = (float*)smem;             // [64 k][8 wo][9 pad] f32 (18.4 KB)
  u16* alds = (u16*)(smem + 20 * 1024);  // [32 h][64 k][8 wo] u16 (32 KB)

  float red[4][4];
  // ---- round 1: max over h ----
#pragma unroll
  for (int mt = 0; mt < 4; mt++)
#pragma unroll
    for (int r = 0; r < 4; r++) {
      float pm = fmaxf(acc[mt][0][r], acc[mt][1][r]);   // over nt
      pm = fmaxf(pm, __shfl_xor(pm, 8));                // over hh
      red[mt][r] = pm;                                  // partial over 4 h
    }
  if (hh == 0) {
#pragma unroll
    for (int mt = 0; mt < 4; mt++)
#pragma unroll
      for (int r = 0; r < 4; r++)
        scr[((mt * 16 + q * 4 + r) * 8 + wo) * 9 + wv] = red[mt][r];
  }
  __syncthreads();
  float mx[4][4];
#pragma unroll
  for (int mt = 0; mt < 4; mt++)
#pragma unroll
    for (int r = 0; r < 4; r++) {
      const float* p = scr + ((mt * 16 + q * 4 + r) * 8 + wo) * 9;
      float m0 = fmaxf(fmaxf(p[0], p[1]), fmaxf(p[2], p[3]));
      float m1 = fmaxf(fmaxf(p[4], p[5]), fmaxf(p[6], p[7]));
      mx[mt][r] = fmaxf(m0, m1);
    }
  __syncthreads();                       // all round-1 reads done
  // ---- round 2: exp & sum over h ----
#pragma unroll
  for (int mt = 0; mt < 4; mt++)
#pragma unroll
    for (int r = 0; r < 4; r++) {
      float p0 = __expf(acc[mt][0][r] - mx[mt][r]);
      float p1 = __expf(acc[mt][1][r] - mx[mt][r]);
      acc[mt][0][r] = p0; acc[mt][1][r] = p1;
      float ps = p0 + p1;
      ps += __shfl_xor(ps, 8);
      red[mt][r] = ps;
    }
  if (hh == 0) {
#pragma unroll
    for (int mt = 0; mt < 4; mt++)
#pragma unroll
      for (int r = 0; r < 4; r++)
        scr[((mt * 16 + q * 4 + r) * 8 + wo) * 9 + wv] = red[mt][r];
  }
  __syncthreads();
  float inv[4][4];
#pragma unroll
  for (int mt = 0; mt < 4; mt++)
#pragma unroll
    for (int r = 0; r < 4; r++) {
      const float* p = scr + ((mt * 16 + q * 4 + r) * 8 + wo) * 9;
      float s8 = ((p[0] + p[1]) + (p[2] + p[3])) + ((p[4] + p[5]) + (p[6] + p[7]));
      inv[mt][r] = 1.0f / s8;
    }
  // ---- a -> LDS slab (disjoint from scratch) ----
#pragma unroll
  for (int mt = 0; mt < 4; mt++)
#pragma unroll
    for (int nt = 0; nt < 2; nt++)
#pragma unroll
      for (int r = 0; r < 4; r++) {
        const int h = wv * 4 + nt * 2 + hh;
        const int kk = mt * 16 + q * 4 + r;
        alds[(h * 64 + kk) * 8 + wo] = bf1(acc[mt][nt][r] * inv[mt][r]);
      }
  __syncthreads();
  // ---- cooperative global write: [b][h][k][32 w], 16 B per (h,k) ----
  u16* ab = apad + ((size_t)b << 16) + ws * 8;
#pragma unroll
  for (int i = 0; i < 4; i++) {
    const int idx = tid + i * 512;           // (h,k): h = idx>>6, k = idx&63
    *(f32x4*)(ab + (size_t)idx * 32) = *(const f32x4*)(alds + (size_t)idx * 8);
  }
}

// ---------------- K2: aggregation + fused normalize (no LDS, no barriers) --
// grid 512 = (dt 8)*(b 64); block 256 = 4 waves; wave: 64k x 16d; 32 n-iters.
__global__ __launch_bounds__(256, 2) void k2_aggregate(
    const float* __restrict__ x, const u16* __restrict__ apad,
    const float* __restrict__ cc, float* __restrict__ yw)
{
  const int blk = blockIdx.x;
  const int b = blk & 63, dt = blk >> 6;       // XCD = b%8 (same as F1's b)
  const int tid = threadIdx.x, lane = tid & 63, wv = tid >> 6;
  const int row = lane & 15, q = lane >> 4;

  const float* px0 = x + ((size_t)b << 19) + (size_t)(dt * 64 + wv * 16 + row) * 1024 + q * 8;
  const u16* ab = apad + ((size_t)b << 16) + (size_t)row * 32 + q * 8;

  f32x4 acc[4];
#pragma unroll
  for (int mt = 0; mt < 4; mt++) acc[mt] = (f32x4){0.f, 0.f, 0.f, 0.f};

  f32x4 xp0[4], xp1[4];                        // x ring, depth 4 (HBM)
  short8 ap[3][4];                             // a ring, depth 3 slots (L2)
#pragma unroll
  for (int j = 0; j < 4; j++) {
    xp0[j] = *(const f32x4*)(px0 + j * 32);
    xp1[j] = *(const f32x4*)(px0 + j * 32 + 4);
  }
#pragma unroll
  for (int j = 0; j < 2; j++)
#pragma unroll
    for (int mt = 0; mt < 4; mt++)
      ap[j][mt] = *(const short8*)(ab + (size_t)j * 2048 + mt * 512);

#pragma unroll
  for (int i = 0; i < 32; i++) {
    const f32x4 c0 = xp0[i & 3], c1 = xp1[i & 3];
    S8u t;
    t.q[0] = pk2(c0[0], c0[1]); t.q[1] = pk2(c0[2], c0[3]);
    t.q[2] = pk2(c1[0], c1[1]); t.q[3] = pk2(c1[2], c1[3]);
    const short8 bfv = t.s;
#pragma unroll
    for (int mt = 0; mt < 4; mt++)
      acc[mt] = __builtin_amdgcn_mfma_f32_16x16x32_bf16(ap[i % 3][mt], bfv, acc[mt], 0, 0, 0);
    if (i + 4 < 32) {
      xp0[i & 3] = *(const f32x4*)(px0 + (i + 4) * 32);
      xp1[i & 3] = *(const f32x4*)(px0 + (i + 4) * 32 + 4);
    }
    if (i + 2 < 32) {
#pragma unroll
      for (int mt = 0; mt < 4; mt++)
        ap[(i + 2) % 3][mt] = *(const short8*)(ab + (size_t)(i + 2) * 2048 + mt * 512);
    }
  }

  // epilogue: lane holds 16 k's for d = dcol; norm over k wave-local (quads)
  const int dcol = dt * 64 + wv * 16 + row;
  float v[16]; float ss = 0.f;
#pragma unroll
  for (int mt = 0; mt < 4; mt++)
#pragma unroll
    for (int r = 0; r < 4; r++) {
      const int k = mt * 16 + q * 4 + r;
      const float tv = acc[mt][r] - 32.0f * cc[k * 512 + dcol];  // Sum_n a = 32 exact
      v[mt * 4 + r] = tv; ss += tv * tv;
    }
  ss += __shfl_xor(ss, 16);
  ss += __shfl_xor(ss, 32);
  const float rn = 1.0f / fmaxf(sqrtf(ss), 1e-12f);  // 2nd normalize is identity
  float* yb = yw + ((size_t)b << 15) + dcol;
#pragma unroll
  for (int mt = 0; mt < 4; mt++)
#pragma unroll
    for (int r = 0; r < 4; r++)
      yb[(size_t)(mt * 16 + q * 4 + r) << 9] = v[mt * 4 + r] * rn;
}

// ---------------- K3: (B,K,D) -> (D,K,B) ----------------
__global__ __launch_bounds__(256) void k3_transpose(
    const float* __restrict__ yw, float* __restrict__ out)
{
  const int blk = blockIdx.x;
  const int k = blk & 63;
  const int dt = blk >> 6;
  const int d0 = dt * 64;
  const int tid = threadIdx.x;
  __shared__ float T[64][68];
  {
    const int bl = tid >> 2, seg = tid & 3;
    const float* src = yw + (size_t)bl * 32768 + k * 512 + d0 + seg * 16;
#pragma unroll
    for (int i = 0; i < 4; i++) {
      f32x4 v = *(const f32x4*)(src + i * 4);
#pragma unroll
      for (int jj = 0; jj < 4; jj++) T[seg * 16 + i * 4 + jj][bl] = v[jj];
    }
  }
  __syncthreads();
  {
    const int dl = tid >> 2, bseg = tid & 3;
    float* dst = out + (size_t)(d0 + dl) * 4096 + k * 64 + bseg * 16;
    const float* srcT = &T[dl][bseg * 16];
#pragma unroll
    for (int i = 0; i < 4; i++)
      *(f32x4*)(dst + i * 4) = *(const f32x4*)(srcT + i * 4);
  }
}

extern "C" void kernel_launch(void* const* d_in, const int* in_sizes, int n_in,
                              void* d_out, int out_size, void* d_ws, size_t ws_size,
                              hipStream_t stream) {
  const float* x = (const float*)d_in[0];
  const float* w = (const float*)d_in[1];
  const float* c = (const float*)d_in[2];
  float* out = (float*)d_out;
  char* ws = (char*)d_ws;
  u16*   apad = (u16*)(ws + (size_t)16 * 1024 * 1024);       //  8 MiB a image
  float* yw   = (float*)(ws + (size_t)26 * 1024 * 1024);     //  8 MiB (B,K,D)
  u16*   wsw  = (u16*)(ws + (size_t)34 * 1024 * 1024);       // 64 KiB w image
  k0_packw       <<<dim3(32),  dim3(256), 0, stream>>>(w, wsw);
  f1_feat_softmax<<<dim3(256), dim3(512), 0, stream>>>(x, wsw, apad);
  k2_aggregate   <<<dim3(512), dim3(256), 0, stream>>>(x, apad, c, yw);
  k3_transpose   <<<dim3(512), dim3(256), 0, stream>>>(yw, out);
}

// Round 4
// 230.695 us; speedup vs baseline: 1.0848x; 1.0848x over previous
//
#include <hip/hip_runtime.h>

// NetVladCNN: B=64, D=512, H=W=32 (N=1024), K=64
// K0 : pack w f32 -> bf16 padded LDS-image (16 d-blocks)[64 k][80 B] in ws
// K1 : feat = w @ x[b] per (b, 128n-tile). x staged via global_load_lds (async,
//      double-buffered); w frags from pre-padded bf16 image (conflict-free b128).
// K1b: softmax over H; vectorized dwordx4 loads + shfl-xor h-reduce; writes a
//      as bf16 padded image (b, n-block)[64 k][80 B]
// K2 : V = a @ x^T - 32*c; a via glds contiguous image, x via pipelined reg
//      loads; grid 1024 x 128 thr (4 blocks/CU, 2-wave blocks) for block-level
//      latency slip; fused L2-normalize over k. -> yw (B,K,D)
// K3 : transpose -> out (D,K,B)

typedef __attribute__((ext_vector_type(8))) short short8;
typedef __attribute__((ext_vector_type(4))) float f32x4;
typedef unsigned short u16;
typedef unsigned int u32;

union S8u { u32 q[4]; short8 s; };

__device__ __forceinline__ u32 pk2(float lo, float hi) {  // RNE bf16 pair pack
  union { float f; u32 u; } a, b; a.f = lo; b.f = hi;
  u32 xl = (a.u + 0x7fffu + ((a.u >> 16) & 1u)) >> 16;
  u32 xh = (b.u + 0x7fffu + ((b.u >> 16) & 1u)) & 0xffff0000u;
  return xl | xh;
}

typedef const __attribute__((address_space(1))) u32 GU32;
typedef __attribute__((address_space(3))) u32 LU32;
__device__ __forceinline__ void glds16(const void* g, void* l) {
  __builtin_amdgcn_global_load_lds((GU32*)g, (LU32*)l, 16, 0, 0);
}

// ---------------- K0: pack w into padded bf16 image ----------------
// wsw image: [i=d-block 16][k 64][40 u16] (32 data + 8 pad) = 80 KB
__global__ __launch_bounds__(256) void k0_packw(
    const float* __restrict__ w, u16* __restrict__ wsw)
{
  const int tg = blockIdx.x * 256 + threadIdx.x;   // 8192 threads
  const int dd4 = tg & 7, i = (tg >> 3) & 15, k = tg >> 7;
  f32x4 v = *(const f32x4*)(w + k * 512 + i * 32 + dd4 * 4);
  u32* dst = (u32*)(wsw + ((size_t)i * 64 + k) * 40 + dd4 * 4);
  dst[0] = pk2(v[0], v[1]);
  dst[1] = pk2(v[2], v[3]);
}

// ---------------- K1: features GEMM (glds double-buffer) ----------------
// grid 512 = (ntile 8)*(b 64); block 256 = 4 waves; block tile 64k x 128n, K=512.
__global__ __launch_bounds__(256, 2) void k1_features(
    const float* __restrict__ x, const u16* __restrict__ wsw,
    float* __restrict__ feat)
{
  const int blk = blockIdx.x;
  const int b = blk & 63, nt8 = blk >> 6;          // XCD = b%8
  const int nb = nt8 * 128;
  const int tid = threadIdx.x, lane = tid & 63, wv = tid >> 6;
  const int row = lane & 15, q = lane >> 4;

  __shared__ __align__(16) float xs[2][32][128];   // 32 KB
  __shared__ __align__(16) u16 wls[2][64][40];     // 10 KB

  const char* xbase = (const char*)(x + ((size_t)b << 19) + nb);
  const char* wbase = (const char*)wsw;
  const int dd0 = tid >> 5, cby = (tid & 31) * 16; // x glds decomposition

  f32x4 acc[4][2];
#pragma unroll
  for (int mt = 0; mt < 4; mt++)
#pragma unroll
    for (int nt = 0; nt < 2; nt++) acc[mt][nt] = (f32x4){0.f, 0.f, 0.f, 0.f};

#define STAGE1(d0, buf)                                                        \
  {                                                                            \
    char* lx = (char*)&xs[buf][0][0];                                          \
    _Pragma("unroll")                                                          \
    for (int j = 0; j < 4; j++) {                                              \
      const int dd = j * 8 + dd0;                                              \
      glds16(xbase + (size_t)((d0) + dd) * 4096 + cby,                         \
             lx + j * 4096 + tid * 16);                                        \
    }                                                                          \
    char* lw = (char*)&wls[buf][0][0];                                         \
    const char* gw = wbase + (size_t)((d0) >> 5) * 5120;                       \
    glds16(gw + tid * 16, lw + tid * 16);                                      \
    if (tid < 64) glds16(gw + 4096 + tid * 16, lw + 4096 + tid * 16);          \
  }

  STAGE1(0, 0);
  for (int i = 0; i < 16; i++) {
    const int buf = i & 1;
    __syncthreads();                        // drains glds for buf (vmcnt(0))
    if (i < 15) STAGE1((i + 1) * 32, buf ^ 1);

    short8 af[4];
#pragma unroll
    for (int mt = 0; mt < 4; mt++)
      af[mt] = *(const short8*)&wls[buf][mt * 16 + row][q * 8];
    short8 bfv[2];
#pragma unroll
    for (int nt = 0; nt < 2; nt++) {
      const int n = wv * 32 + nt * 16 + row;
      const int d8 = q * 8;
      float v0 = xs[buf][d8 + 0][n], v1 = xs[buf][d8 + 1][n];
      float v2 = xs[buf][d8 + 2][n], v3 = xs[buf][d8 + 3][n];
      float v4 = xs[buf][d8 + 4][n], v5 = xs[buf][d8 + 5][n];
      float v6 = xs[buf][d8 + 6][n], v7 = xs[buf][d8 + 7][n];
      S8u t;
      t.q[0] = pk2(v0, v1); t.q[1] = pk2(v2, v3);
      t.q[2] = pk2(v4, v5); t.q[3] = pk2(v6, v7);
      bfv[nt] = t.s;
    }
#pragma unroll
    for (int nt = 0; nt < 2; nt++)
#pragma unroll
      for (int mt = 0; mt < 4; mt++)
        acc[mt][nt] = __builtin_amdgcn_mfma_f32_16x16x32_bf16(af[mt], bfv[nt], acc[mt][nt], 0, 0, 0);
  }
#undef STAGE1

  float* fb = feat + ((size_t)b << 16);
  const int nbw = nb + wv * 32;
#pragma unroll
  for (int mt = 0; mt < 4; mt++)
#pragma unroll
    for (int nt = 0; nt < 2; nt++)
#pragma unroll
      for (int r = 0; r < 4; r++)   // C layout: col=lane&15, row=q*4+r
        fb[(mt * 16 + q * 4 + r) * 1024 + nbw + nt * 16 + row] = acc[mt][nt][r];
}

// ---------------- K1b: softmax over H -> padded a image (vectorized) -------
// apad image: [b][h=n-block 32][k 64][40 u16]
// per wave: one (b,k) row. lane = (hq = lane>>3) x (wl = (lane&7)*4 w-cols).
__global__ __launch_bounds__(256) void k1b_softmax(
    const float* __restrict__ feat, u16* __restrict__ apad)
{
  const int tid = threadIdx.x, wv = tid >> 6, lane = tid & 63;
  const int rid = blockIdx.x * 4 + wv;         // rid = b*64 + k
  const int b = rid >> 6, k = rid & 63;
  const float* f = feat + ((size_t)rid << 10);
  const int wl = (lane & 7) * 4;               // 4 w-columns per lane
  const int hq = lane >> 3;                    // h = hq + r*8

  f32x4 v[4];
#pragma unroll
  for (int r = 0; r < 4; r++)
    v[r] = *(const f32x4*)(f + (hq + r * 8) * 32 + wl);

  f32x4 m = v[0];
#pragma unroll
  for (int r = 1; r < 4; r++)
#pragma unroll
    for (int c = 0; c < 4; c++) m[c] = fmaxf(m[c], v[r][c]);
#pragma unroll
  for (int mk = 8; mk <= 32; mk <<= 1)
#pragma unroll
    for (int c = 0; c < 4; c++) m[c] = fmaxf(m[c], __shfl_xor(m[c], mk));

  f32x4 s = (f32x4){0.f, 0.f, 0.f, 0.f};
#pragma unroll
  for (int r = 0; r < 4; r++)
#pragma unroll
    for (int c = 0; c < 4; c++) { v[r][c] = __expf(v[r][c] - m[c]); s[c] += v[r][c]; }
#pragma unroll
  for (int mk = 8; mk <= 32; mk <<= 1)
#pragma unroll
    for (int c = 0; c < 4; c++) s[c] += __shfl_xor(s[c], mk);

  f32x4 inv;
#pragma unroll
  for (int c = 0; c < 4; c++) inv[c] = 1.0f / s[c];

#pragma unroll
  for (int r = 0; r < 4; r++) {
    const int h = hq + r * 8;
    u32* dst = (u32*)(apad + ((size_t)(b * 32 + h) * 64 + k) * 40 + wl);
    dst[0] = pk2(v[r][0] * inv[0], v[r][1] * inv[1]);
    dst[1] = pk2(v[r][2] * inv[2], v[r][3] * inv[3]);
  }
}

// ---------------- K2: aggregation + fused normalize ----------------
// grid 1024 = (dt 16)*(b 64); block 128 = 2 waves; wave: 64k x 16d; 32 n-iters.
// 4 blocks/CU: 2-wave barriers, independent blocks absorb staging stalls.
__global__ __launch_bounds__(128, 2) void k2_aggregate(
    const float* __restrict__ x, const u16* __restrict__ apad,
    const float* __restrict__ cc, float* __restrict__ yw)
{
  const int blk = blockIdx.x;
  const int b = blk & 63, dt = blk >> 6;       // dt 0..15, XCD = b%8
  const int tid = threadIdx.x, lane = tid & 63, wv = tid >> 6;
  const int row = lane & 15, q = lane >> 4;

  __shared__ __align__(16) u16 als[2][64][40];   // 10 KB

  const char* abase = (const char*)(apad + (size_t)b * 32 * 64 * 40);
  const float* px0 = x + ((size_t)b << 19) + (size_t)(dt * 32 + wv * 16 + row) * 1024 + q * 8;

#define STAGEA(i, buf)                                                         \
  {                                                                            \
    char* la = (char*)&als[buf][0][0];                                         \
    const char* ga = abase + (size_t)(i) * 5120;                               \
    glds16(ga + tid * 16, la + tid * 16);                                      \
    glds16(ga + 2048 + tid * 16, la + 2048 + tid * 16);                        \
    if (tid < 64) glds16(ga + 4096 + tid * 16, la + 4096 + tid * 16);          \
  }

  f32x4 acc[4];
#pragma unroll
  for (int mt = 0; mt < 4; mt++) acc[mt] = (f32x4){0.f, 0.f, 0.f, 0.f};

  STAGEA(0, 0);
  f32x4 c0 = *(const f32x4*)px0;
  f32x4 c1 = *(const f32x4*)(px0 + 4);
  f32x4 p0, p1;
  for (int i = 0; i < 32; i++) {
    const int buf = i & 1;
    __syncthreads();                        // drains glds + reg loads from i-1
    if (i < 31) {
      STAGEA(i + 1, buf ^ 1);
      p0 = *(const f32x4*)(px0 + (i + 1) * 32);
      p1 = *(const f32x4*)(px0 + (i + 1) * 32 + 4);
    }
    S8u t;
    t.q[0] = pk2(c0[0], c0[1]); t.q[1] = pk2(c0[2], c0[3]);
    t.q[2] = pk2(c1[0], c1[1]); t.q[3] = pk2(c1[2], c1[3]);
    const short8 bfv = t.s;
#pragma unroll
    for (int mt = 0; mt < 4; mt++) {
      short8 af = *(const short8*)&als[buf][mt * 16 + row][q * 8];
      acc[mt] = __builtin_amdgcn_mfma_f32_16x16x32_bf16(af, bfv, acc[mt], 0, 0, 0);
    }
    c0 = p0; c1 = p1;
  }
#undef STAGEA

  // epilogue: lane holds 16 k's for d = dcol; norm over k wave-local (quads)
  const int dcol = dt * 32 + wv * 16 + row;
  float v[16]; float ss = 0.f;
#pragma unroll
  for (int mt = 0; mt < 4; mt++)
#pragma unroll
    for (int r = 0; r < 4; r++) {
      const int k = mt * 16 + q * 4 + r;
      const float tv = acc[mt][r] - 32.0f * cc[k * 512 + dcol];  // Sum_n a = 32 exact
      v[mt * 4 + r] = tv; ss += tv * tv;
    }
  ss += __shfl_xor(ss, 16);
  ss += __shfl_xor(ss, 32);
  const float rn = 1.0f / fmaxf(sqrtf(ss), 1e-12f);  // 2nd normalize is identity
  float* yb = yw + ((size_t)b << 15) + dcol;
#pragma unroll
  for (int mt = 0; mt < 4; mt++)
#pragma unroll
    for (int r = 0; r < 4; r++)
      yb[(size_t)(mt * 16 + q * 4 + r) << 9] = v[mt * 4 + r] * rn;
}

// ---------------- K3: (B,K,D) -> (D,K,B) ----------------
__global__ __launch_bounds__(256) void k3_transpose(
    const float* __restrict__ yw, float* __restrict__ out)
{
  const int blk = blockIdx.x;
  const int k = blk & 63;
  const int dt = blk >> 6;
  const int d0 = dt * 64;
  const int tid = threadIdx.x;
  __shared__ float T[64][68];
  {
    const int bl = tid >> 2, seg = tid & 3;
    const float* src = yw + (size_t)bl * 32768 + k * 512 + d0 + seg * 16;
#pragma unroll
    for (int i = 0; i < 4; i++) {
      f32x4 v = *(const f32x4*)(src + i * 4);
#pragma unroll
      for (int jj = 0; jj < 4; jj++) T[seg * 16 + i * 4 + jj][bl] = v[jj];
    }
  }
  __syncthreads();
  {
    const int dl = tid >> 2, bseg = tid & 3;
    float* dst = out + (size_t)(d0 + dl) * 4096 + k * 64 + bseg * 16;
    const float* srcT = &T[dl][bseg * 16];
#pragma unroll
    for (int i = 0; i < 4; i++)
      *(f32x4*)(dst + i * 4) = *(const f32x4*)(srcT + i * 4);
  }
}

extern "C" void kernel_launch(void* const* d_in, const int* in_sizes, int n_in,
                              void* d_out, int out_size, void* d_ws, size_t ws_size,
                              hipStream_t stream) {
  const float* x = (const float*)d_in[0];
  const float* w = (const float*)d_in[1];
  const float* c = (const float*)d_in[2];
  float* out = (float*)d_out;
  char* ws = (char*)d_ws;
  float* feat = (float*)ws;                                  // 16 MiB f32 logits
  u16*   apad = (u16*)(ws + (size_t)16 * 1024 * 1024);       // 10 MiB padded a image
  float* yw   = (float*)(ws + (size_t)26 * 1024 * 1024);     //  8 MiB (B,K,D)
  u16*   wsw  = (u16*)(ws + (size_t)34 * 1024 * 1024);       // 80 KiB padded w image
  k0_packw    <<<dim3(32),   dim3(256), 0, stream>>>(w, wsw);
  k1_features <<<dim3(512),  dim3(256), 0, stream>>>(x, wsw, feat);
  k1b_softmax <<<dim3(1024), dim3(256), 0, stream>>>(feat, apad);
  k2_aggregate<<<dim3(1024), dim3(128), 0, stream>>>(x, apad, c, yw);
  k3_transpose<<<dim3(512),  dim3(256), 0, stream>>>(yw, out);
}

// Round 5
// 230.669 us; speedup vs baseline: 1.0850x; 1.0001x over previous
//
#include <hip/hip_runtime.h>

// NetVladCNN: B=64, D=512, H=W=32 (N=1024), K=64
// K0 : pack w f32 -> bf16 padded LDS-image (16 d-blocks)[64 k][80 B] in ws
// K1 : feat = w @ x[b] per (b, 128n-tile). x staged via global_load_lds (async,
//      double-buffered); w frags from pre-padded bf16 image (conflict-free b128).
//      bf16 repack via v_cvt_pk_bf16_f32 (1 VALU/pair vs ~7 for manual RNE).
// K1b: softmax over H; vectorized dwordx4 loads + shfl-xor h-reduce; writes a
//      as bf16 padded image (b, n-block)[64 k][80 B]
// K2 : V = a @ x^T - 32*c; a via glds contiguous image, x via pipelined reg
//      loads; grid 1024 x 128 thr (4 blocks/CU, 2-wave blocks); cvt_pk repack;
//      fused L2-normalize over k. -> yw (B,K,D)
// K3 : transpose -> out (D,K,B)

typedef __attribute__((ext_vector_type(8))) short short8;
typedef __attribute__((ext_vector_type(4))) float f32x4;
typedef unsigned short u16;
typedef unsigned int u32;

union S8u { u32 q[4]; short8 s; };

__device__ __forceinline__ u32 pk2(float lo, float hi) {  // RNE bf16 pair pack
  union { float f; u32 u; } a, b; a.f = lo; b.f = hi;
  u32 xl = (a.u + 0x7fffu + ((a.u >> 16) & 1u)) >> 16;
  u32 xh = (b.u + 0x7fffu + ((b.u >> 16) & 1u)) & 0xffff0000u;
  return xl | xh;
}

__device__ __forceinline__ u32 cvtpk(float lo, float hi) {  // HW RNE bf16 pack
  u32 r;
  asm("v_cvt_pk_bf16_f32 %0, %1, %2" : "=v"(r) : "v"(lo), "v"(hi));
  return r;
}

typedef const __attribute__((address_space(1))) u32 GU32;
typedef __attribute__((address_space(3))) u32 LU32;
__device__ __forceinline__ void glds16(const void* g, void* l) {
  __builtin_amdgcn_global_load_lds((GU32*)g, (LU32*)l, 16, 0, 0);
}

// ---------------- K0: pack w into padded bf16 image ----------------
// wsw image: [i=d-block 16][k 64][40 u16] (32 data + 8 pad) = 80 KB
__global__ __launch_bounds__(256) void k0_packw(
    const float* __restrict__ w, u16* __restrict__ wsw)
{
  const int tg = blockIdx.x * 256 + threadIdx.x;   // 8192 threads
  const int dd4 = tg & 7, i = (tg >> 3) & 15, k = tg >> 7;
  f32x4 v = *(const f32x4*)(w + k * 512 + i * 32 + dd4 * 4);
  u32* dst = (u32*)(wsw + ((size_t)i * 64 + k) * 40 + dd4 * 4);
  dst[0] = pk2(v[0], v[1]);
  dst[1] = pk2(v[2], v[3]);
}

// ---------------- K1: features GEMM (glds double-buffer) ----------------
// grid 512 = (ntile 8)*(b 64); block 256 = 4 waves; block tile 64k x 128n, K=512.
__global__ __launch_bounds__(256, 2) void k1_features(
    const float* __restrict__ x, const u16* __restrict__ wsw,
    float* __restrict__ feat)
{
  const int blk = blockIdx.x;
  const int b = blk & 63, nt8 = blk >> 6;          // XCD = b%8
  const int nb = nt8 * 128;
  const int tid = threadIdx.x, lane = tid & 63, wv = tid >> 6;
  const int row = lane & 15, q = lane >> 4;

  __shared__ __align__(16) float xs[2][32][128];   // 32 KB
  __shared__ __align__(16) u16 wls[2][64][40];     // 10 KB

  const char* xbase = (const char*)(x + ((size_t)b << 19) + nb);
  const char* wbase = (const char*)wsw;
  const int dd0 = tid >> 5, cby = (tid & 31) * 16; // x glds decomposition

  f32x4 acc[4][2];
#pragma unroll
  for (int mt = 0; mt < 4; mt++)
#pragma unroll
    for (int nt = 0; nt < 2; nt++) acc[mt][nt] = (f32x4){0.f, 0.f, 0.f, 0.f};

#define STAGE1(d0, buf)                                                        \
  {                                                                            \
    char* lx = (char*)&xs[buf][0][0];                                          \
    _Pragma("unroll")                                                          \
    for (int j = 0; j < 4; j++) {                                              \
      const int dd = j * 8 + dd0;                                              \
      glds16(xbase + (size_t)((d0) + dd) * 4096 + cby,                         \
             lx + j * 4096 + tid * 16);                                        \
    }                                                                          \
    char* lw = (char*)&wls[buf][0][0];                                         \
    const char* gw = wbase + (size_t)((d0) >> 5) * 5120;                       \
    glds16(gw + tid * 16, lw + tid * 16);                                      \
    if (tid < 64) glds16(gw + 4096 + tid * 16, lw + 4096 + tid * 16);          \
  }

  STAGE1(0, 0);
  for (int i = 0; i < 16; i++) {
    const int buf = i & 1;
    __syncthreads();                        // drains glds for buf (vmcnt(0))
    if (i < 15) STAGE1((i + 1) * 32, buf ^ 1);

    short8 af[4];
#pragma unroll
    for (int mt = 0; mt < 4; mt++)
      af[mt] = *(const short8*)&wls[buf][mt * 16 + row][q * 8];
    short8 bfv[2];
#pragma unroll
    for (int nt = 0; nt < 2; nt++) {
      const int n = wv * 32 + nt * 16 + row;
      const int d8 = q * 8;
      float v0 = xs[buf][d8 + 0][n], v1 = xs[buf][d8 + 1][n];
      float v2 = xs[buf][d8 + 2][n], v3 = xs[buf][d8 + 3][n];
      float v4 = xs[buf][d8 + 4][n], v5 = xs[buf][d8 + 5][n];
      float v6 = xs[buf][d8 + 6][n], v7 = xs[buf][d8 + 7][n];
      S8u t;
      t.q[0] = cvtpk(v0, v1); t.q[1] = cvtpk(v2, v3);
      t.q[2] = cvtpk(v4, v5); t.q[3] = cvtpk(v6, v7);
      bfv[nt] = t.s;
    }
#pragma unroll
    for (int nt = 0; nt < 2; nt++)
#pragma unroll
      for (int mt = 0; mt < 4; mt++)
        acc[mt][nt] = __builtin_amdgcn_mfma_f32_16x16x32_bf16(af[mt], bfv[nt], acc[mt][nt], 0, 0, 0);
  }
#undef STAGE1

  float* fb = feat + ((size_t)b << 16);
  const int nbw = nb + wv * 32;
#pragma unroll
  for (int mt = 0; mt < 4; mt++)
#pragma unroll
    for (int nt = 0; nt < 2; nt++)
#pragma unroll
      for (int r = 0; r < 4; r++)   // C layout: col=lane&15, row=q*4+r
        fb[(mt * 16 + q * 4 + r) * 1024 + nbw + nt * 16 + row] = acc[mt][nt][r];
}

// ---------------- K1b: softmax over H -> padded a image (vectorized) -------
// apad image: [b][h=n-block 32][k 64][40 u16]
// per wave: one (b,k) row. lane = (hq = lane>>3) x (wl = (lane&7)*4 w-cols).
__global__ __launch_bounds__(256) void k1b_softmax(
    const float* __restrict__ feat, u16* __restrict__ apad)
{
  const int tid = threadIdx.x, wv = tid >> 6, lane = tid & 63;
  const int rid = blockIdx.x * 4 + wv;         // rid = b*64 + k
  const int b = rid >> 6, k = rid & 63;
  const float* f = feat + ((size_t)rid << 10);
  const int wl = (lane & 7) * 4;               // 4 w-columns per lane
  const int hq = lane >> 3;                    // h = hq + r*8

  f32x4 v[4];
#pragma unroll
  for (int r = 0; r < 4; r++)
    v[r] = *(const f32x4*)(f + (hq + r * 8) * 32 + wl);

  f32x4 m = v[0];
#pragma unroll
  for (int r = 1; r < 4; r++)
#pragma unroll
    for (int c = 0; c < 4; c++) m[c] = fmaxf(m[c], v[r][c]);
#pragma unroll
  for (int mk = 8; mk <= 32; mk <<= 1)
#pragma unroll
    for (int c = 0; c < 4; c++) m[c] = fmaxf(m[c], __shfl_xor(m[c], mk));

  f32x4 s = (f32x4){0.f, 0.f, 0.f, 0.f};
#pragma unroll
  for (int r = 0; r < 4; r++)
#pragma unroll
    for (int c = 0; c < 4; c++) { v[r][c] = __expf(v[r][c] - m[c]); s[c] += v[r][c]; }
#pragma unroll
  for (int mk = 8; mk <= 32; mk <<= 1)
#pragma unroll
    for (int c = 0; c < 4; c++) s[c] += __shfl_xor(s[c], mk);

  f32x4 inv;
#pragma unroll
  for (int c = 0; c < 4; c++) inv[c] = 1.0f / s[c];

#pragma unroll
  for (int r = 0; r < 4; r++) {
    const int h = hq + r * 8;
    u32* dst = (u32*)(apad + ((size_t)(b * 32 + h) * 64 + k) * 40 + wl);
    dst[0] = pk2(v[r][0] * inv[0], v[r][1] * inv[1]);
    dst[1] = pk2(v[r][2] * inv[2], v[r][3] * inv[3]);
  }
}

// ---------------- K2: aggregation + fused normalize ----------------
// grid 1024 = (dt 16)*(b 64); block 128 = 2 waves; wave: 64k x 16d; 32 n-iters.
// 4 blocks/CU: 2-wave barriers, independent blocks absorb staging stalls.
__global__ __launch_bounds__(128, 2) void k2_aggregate(
    const float* __restrict__ x, const u16* __restrict__ apad,
    const float* __restrict__ cc, float* __restrict__ yw)
{
  const int blk = blockIdx.x;
  const int b = blk & 63, dt = blk >> 6;       // dt 0..15, XCD = b%8
  const int tid = threadIdx.x, lane = tid & 63, wv = tid >> 6;
  const int row = lane & 15, q = lane >> 4;

  __shared__ __align__(16) u16 als[2][64][40];   // 10 KB

  const char* abase = (const char*)(apad + (size_t)b * 32 * 64 * 40);
  const float* px0 = x + ((size_t)b << 19) + (size_t)(dt * 32 + wv * 16 + row) * 1024 + q * 8;

#define STAGEA(i, buf)                                                         \
  {                                                                            \
    char* la = (char*)&als[buf][0][0];                                         \
    const char* ga = abase + (size_t)(i) * 5120;                               \
    glds16(ga + tid * 16, la + tid * 16);                                      \
    glds16(ga + 2048 + tid * 16, la + 2048 + tid * 16);                        \
    if (tid < 64) glds16(ga + 4096 + tid * 16, la + 4096 + tid * 16);          \
  }

  f32x4 acc[4];
#pragma unroll
  for (int mt = 0; mt < 4; mt++) acc[mt] = (f32x4){0.f, 0.f, 0.f, 0.f};

  STAGEA(0, 0);
  f32x4 c0 = *(const f32x4*)px0;
  f32x4 c1 = *(const f32x4*)(px0 + 4);
  f32x4 p0, p1;
  for (int i = 0; i < 32; i++) {
    const int buf = i & 1;
    __syncthreads();                        // drains glds + reg loads from i-1
    if (i < 31) {
      STAGEA(i + 1, buf ^ 1);
      p0 = *(const f32x4*)(px0 + (i + 1) * 32);
      p1 = *(const f32x4*)(px0 + (i + 1) * 32 + 4);
    }
    S8u t;
    t.q[0] = cvtpk(c0[0], c0[1]); t.q[1] = cvtpk(c0[2], c0[3]);
    t.q[2] = cvtpk(c1[0], c1[1]); t.q[3] = cvtpk(c1[2], c1[3]);
    const short8 bfv = t.s;
#pragma unroll
    for (int mt = 0; mt < 4; mt++) {
      short8 af = *(const short8*)&als[buf][mt * 16 + row][q * 8];
      acc[mt] = __builtin_amdgcn_mfma_f32_16x16x32_bf16(af, bfv, acc[mt], 0, 0, 0);
    }
    c0 = p0; c1 = p1;
  }
#undef STAGEA

  // epilogue: lane holds 16 k's for d = dcol; norm over k wave-local (quads)
  const int dcol = dt * 32 + wv * 16 + row;
  float v[16]; float ss = 0.f;
#pragma unroll
  for (int mt = 0; mt < 4; mt++)
#pragma unroll
    for (int r = 0; r < 4; r++) {
      const int k = mt * 16 + q * 4 + r;
      const float tv = acc[mt][r] - 32.0f * cc[k * 512 + dcol];  // Sum_n a = 32 exact
      v[mt * 4 + r] = tv; ss += tv * tv;
    }
  ss += __shfl_xor(ss, 16);
  ss += __shfl_xor(ss, 32);
  const float rn = 1.0f / fmaxf(sqrtf(ss), 1e-12f);  // 2nd normalize is identity
  float* yb = yw + ((size_t)b << 15) + dcol;
#pragma unroll
  for (int mt = 0; mt < 4; mt++)
#pragma unroll
    for (int r = 0; r < 4; r++)
      yb[(size_t)(mt * 16 + q * 4 + r) << 9] = v[mt * 4 + r] * rn;
}

// ---------------- K3: (B,K,D) -> (D,K,B) ----------------
__global__ __launch_bounds__(256) void k3_transpose(
    const float* __restrict__ yw, float* __restrict__ out)
{
  const int blk = blockIdx.x;
  const int k = blk & 63;
  const int dt = blk >> 6;
  const int d0 = dt * 64;
  const int tid = threadIdx.x;
  __shared__ float T[64][68];
  {
    const int bl = tid >> 2, seg = tid & 3;
    const float* src = yw + (size_t)bl * 32768 + k * 512 + d0 + seg * 16;
#pragma unroll
    for (int i = 0; i < 4; i++) {
      f32x4 v = *(const f32x4*)(src + i * 4);
#pragma unroll
      for (int jj = 0; jj < 4; jj++) T[seg * 16 + i * 4 + jj][bl] = v[jj];
    }
  }
  __syncthreads();
  {
    const int dl = tid >> 2, bseg = tid & 3;
    float* dst = out + (size_t)(d0 + dl) * 4096 + k * 64 + bseg * 16;
    const float* srcT = &T[dl][bseg * 16];
#pragma unroll
    for (int i = 0; i < 4; i++)
      *(f32x4*)(dst + i * 4) = *(const f32x4*)(srcT + i * 4);
  }
}

extern "C" void kernel_launch(void* const* d_in, const int* in_sizes, int n_in,
                              void* d_out, int out_size, void* d_ws, size_t ws_size,
                              hipStream_t stream) {
  const float* x = (const float*)d_in[0];
  const float* w = (const float*)d_in[1];
  const float* c = (const float*)d_in[2];
  float* out = (float*)d_out;
  char* ws = (char*)d_ws;
  float* feat = (float*)ws;                                  // 16 MiB f32 logits
  u16*   apad = (u16*)(ws + (size_t)16 * 1024 * 1024);       // 10 MiB padded a image
  float* yw   = (float*)(ws + (size_t)26 * 1024 * 1024);     //  8 MiB (B,K,D)
  u16*   wsw  = (u16*)(ws + (size_t)34 * 1024 * 1024);       // 80 KiB padded w image
  k0_packw    <<<dim3(32),   dim3(256), 0, stream>>>(w, wsw);
  k1_features <<<dim3(512),  dim3(256), 0, stream>>>(x, wsw, feat);
  k1b_softmax <<<dim3(1024), dim3(256), 0, stream>>>(feat, apad);
  k2_aggregate<<<dim3(1024), dim3(128), 0, stream>>>(x, apad, c, yw);
  k3_transpose<<<dim3(512),  dim3(256), 0, stream>>>(yw, out);
}